// Round 12
// baseline (232.445 us; speedup 1.0000x reference)
//
#include <hip/hip_runtime.h>
#include <math.h>

typedef unsigned short ushort_t;
typedef unsigned int uint_t;
typedef __attribute__((ext_vector_type(8))) short short8v;   // 8 bf16 = 4 VGPR
typedef __attribute__((ext_vector_type(4))) float f32x4;

#define BB   512
#define TT   243
#define DIMV 512
#define CC   256
#define CHH  128
#define FF   122
#define NKK  122

__device__ __forceinline__ float b2f(ushort_t u) {
  union { uint_t i; float f; } z; z.i = ((uint_t)u) << 16; return z.f;
}
__device__ __forceinline__ ushort_t f2b(float f) {
  union { float f; uint_t i; } z; z.f = f;
  uint_t r = (z.i + 0x7fffu + ((z.i >> 16) & 1u)) >> 16;
  return (ushort_t)r;
}
// packed f32x2 -> bf16x2 in one VALU instr (RNE)
__device__ __forceinline__ uint_t pack2(float a, float b) {
  uint_t r;
  asm("v_cvt_pk_bf16_f32 %0, %1, %2" : "=v"(r) : "v"(a), "v"(b));
  return r;
}
// branchless gelu: A&S 7.1.26 erf, |eps|<=1.5e-7
__device__ __forceinline__ float gelu_f(float x) {
  float z = fabsf(x) * 0.70710678118654752f;
  float t = __builtin_amdgcn_rcpf(fmaf(0.3275911f, z, 1.0f));
  float p = fmaf(1.061405429f, t, -1.453152027f);
  p = fmaf(p, t, 1.421413741f);
  p = fmaf(p, t, -0.284496736f);
  p = fmaf(p, t, 0.254829592f);
  p = p * t;
  float e = __expf(-z * z);
  float erfa = 1.0f - p * e;
  float erfs = copysignf(erfa, x);
  return 0.5f * x * (1.0f + erfs);
}
__device__ __forceinline__ float sigmoid_f(float x) {
  return __builtin_amdgcn_rcpf(1.0f + __expf(-x));
}
union FragU { uint_t u[4]; short8v s; };

// ---------------- prep1: compute_A (blocks 0..121) + weight pack (blocks 122..505) ----------------

__global__ __launch_bounds__(256) void k_prep1(const float* __restrict__ lf, float* __restrict__ A,
    const float* __restrict__ w1, const float* __restrict__ w2,
    ushort_t* __restrict__ w1f, ushort_t* __restrict__ w2f) {
  __shared__ float2 tab[TT];
  int bid = blockIdx.x;
  if (bid < FF) {
    int f = bid;
    int tp = threadIdx.x;
    if (tp < TT) {
      float s, c;
      sincosf(6.28318530717958647692f * (float)tp / (float)TT, &s, &c);
      tab[tp] = make_float2(s, c);
    }
    __syncthreads();
    if (tp >= TT) return;
    float are = 0.f, aim = 0.f;
    int m = 0;
    const float* lrow = lf + (size_t)f * NKK * 2;
    for (int k = 0; k < NKK; ++k) {
      float2 sc = tab[m];
      float lr = lrow[2 * k], li = lrow[2 * k + 1];
      are = fmaf(lr, sc.y, fmaf(li, sc.x, are));
      aim = fmaf(li, sc.y, fmaf(-lr, sc.x, aim));
      m += tp; if (m >= TT) m -= TT;
    }
    A[(f * TT + tp) * 2 + 0] = are;
    A[(f * TT + tp) * 2 + 1] = aim;
  } else {
    int q = (bid - FF) * 256 + threadIdx.x;
    if (q < 49152) {
      int j = q & 7, l = (q >> 3) & 63, ot = (q >> 9) & 3, rest = q >> 11;
      int ks = rest % 12, g = rest / 12;
      int o = ot * 16 + (l & 15);
      int k = ks * 32 + 8 * (l >> 4) + j;
      int dk = k >> 7, i = k & 127;
      w1f[q] = f2b(w1[(g * 64 + o) * 384 + i * 3 + dk]);
    } else if (q < 98304) {
      int q2 = q - 49152;
      int j = q2 & 7, l = (q2 >> 3) & 63, ot = (q2 >> 9) & 7, rest = q2 >> 12;
      int ks = rest % 6, g = rest / 6;
      int o = ot * 16 + (l & 15);
      int k = ks * 32 + 8 * (l >> 4) + j;
      int dk = k >> 6, i = k & 63;
      w2f[q2] = f2b(w2[(g * 128 + o) * 192 + i * 3 + dk]);
    }
  }
}

// F[t][tp] (256x256 zero-padded) in MFMA fragment order:
// Ffrag[((kstep*16 + mt)*64 + lane)*8 + j] = F[mt*16 + lane%16][kstep*32 + (lane/16)*8 + j]
__global__ void k_compute_M(const float* __restrict__ A, ushort_t* __restrict__ Ffrag) {
  __shared__ float2 tab[TT];
  int t = blockIdx.x;            // 0..255
  int tp = threadIdx.x;          // 0..255
  if (tp < TT) {
    float s, c;
    sincosf(6.28318530717958647692f * (float)tp / (float)TT, &s, &c);
    tab[tp] = make_float2(s, c);
  }
  __syncthreads();
  float val = 0.f;
  if (t < TT && tp < TT) {
    float acc = A[tp * 2 + 0];
    int m = t;
    for (int f = 1; f < FF; ++f) {
      float2 sc = tab[m];
      float ar = A[(f * TT + tp) * 2 + 0];
      float ai = A[(f * TT + tp) * 2 + 1];
      acc = fmaf(2.f * ar, sc.y, fmaf(-2.f * ai, sc.x, acc));
      m += t; if (m >= TT) m -= TT;
    }
    val = acc * (1.0f / (float)TT);
  }
  int kstep = tp >> 5, ko = tp & 31, p = ko >> 3, j = ko & 7;
  int mt = t >> 4, row = t & 15, lane = p * 16 + row;
  Ffrag[(((kstep * 16 + mt) * 64) + lane) * 8 + j] = f2b(val);
}

// ---------------- fused main kernel: res blocks + gate blocks, interleaved 1:2 ----------------

#define RST   17    // res LDS row stride (dwords)
#define BT    32
#define NTIL  8     // ceil(243/32)
#define XROWS 36
#define XSTD  130   // dwords per xs row (256 bf16 + pad); stride 2 mod 32 -> b128 conflict-free
#define HROWS 34
#define HSTD  66    // dwords per hs row (128 bf16 + pad); stride 2 mod 32
// smem dwords: gate = 36*130 + 34*66 + 2*4*48 + 2*4*32 = 7564 ; res = 2*64*17 = 2176
#define SMEM_DW 7564

__device__ __forceinline__ void res_path(int rid, uint_t* smem,
    const float* __restrict__ x, const ushort_t* __restrict__ Ffrag, float* __restrict__ out) {
  uint_t* xs = smem;                            // [2][64*RST]
  int b = rid >> 2, c0 = (rid & 3) * 64;
  int tid = threadIdx.x, l = tid & 63, w = tid >> 6;
  const float* xb = x + (size_t)b * TT * DIMV + c0;
  const short8v* Fp = (const short8v*)Ffrag;

  f32x4 acc[4][4];                              // [q = nt-local][m]
#pragma unroll
  for (int q = 0; q < 4; ++q)
#pragma unroll
    for (int m = 0; m < 4; ++m) acc[q][m] = (f32x4){0.f, 0.f, 0.f, 0.f};

  float v0[4], v1[4];
  int cc = tid & 63, kp0 = tid >> 6;

#pragma unroll
  for (int it = 0; it < 4; ++it) {
    int kp = kp0 + 4 * it, tp = 2 * kp;
    v0[it] = (tp < TT) ? xb[(size_t)tp * DIMV + cc] : 0.f;
    v1[it] = (tp + 1 < TT) ? xb[(size_t)(tp + 1) * DIMV + cc] : 0.f;
  }
#pragma unroll
  for (int it = 0; it < 4; ++it) xs[cc * RST + kp0 + 4 * it] = pack2(v0[it], v1[it]);
  __syncthreads();

  for (int ks = 0; ks < 8; ++ks) {
    int cur = ks & 1;
    if (ks < 7) {
#pragma unroll
      for (int it = 0; it < 4; ++it) {
        int kp = kp0 + 4 * it, tp = (ks + 1) * 32 + 2 * kp;
        v0[it] = (tp < TT) ? xb[(size_t)tp * DIMV + cc] : 0.f;
        v1[it] = (tp + 1 < TT) ? xb[(size_t)(tp + 1) * DIMV + cc] : 0.f;
      }
    }
    FragU bfr[4];
#pragma unroll
    for (int q = 0; q < 4; ++q) bfr[q].s = Fp[(ks * 16 + 4 * w + q) * 64 + l];
#pragma unroll
    for (int m = 0; m < 4; ++m) {
      FragU af;
      const uint_t* pp = &xs[cur * (64 * RST) + (16 * m + (l & 15)) * RST + 4 * (l >> 4)];
      af.u[0] = pp[0]; af.u[1] = pp[1]; af.u[2] = pp[2]; af.u[3] = pp[3];
#pragma unroll
      for (int q = 0; q < 4; ++q)
        acc[q][m] = __builtin_amdgcn_mfma_f32_16x16x32_bf16(af.s, bfr[q].s, acc[q][m], 0, 0, 0);
    }
    if (ks < 7) {
#pragma unroll
      for (int it = 0; it < 4; ++it)
        xs[(cur ^ 1) * (64 * RST) + cc * RST + kp0 + 4 * it] = pack2(v0[it], v1[it]);
    }
    __syncthreads();
  }

  float* ob = out + (size_t)b * TT * DIMV + c0;
#pragma unroll
  for (int q = 0; q < 4; ++q) {
    int t = (4 * w + q) * 16 + (l & 15);
    if (t < TT) {
#pragma unroll
      for (int m = 0; m < 4; ++m)
        *(f32x4*)&ob[(size_t)t * DIMV + 16 * m + 4 * (l >> 4)] = acc[q][m];
    }
  }
}

__device__ __forceinline__ void gate_path(int gid, uint_t* smem,
    const float* __restrict__ x,
    const ushort_t* __restrict__ w1f, const float* __restrict__ g1, const float* __restrict__ b1,
    const ushort_t* __restrict__ w2f, const float* __restrict__ g2, const float* __restrict__ b2,
    float* __restrict__ out) {
  uint_t* xs = smem;                            // [36][130]
  uint_t* hs = smem + XROWS * XSTD;             // [34][66]
  float* red1s = (float*)(hs + HROWS * HSTD);   // [4][48]
  float* red1q = red1s + 192;
  float* red2s = red1q + 192;                   // [4][32]
  float* red2q = red2s + 128;
  int b = gid >> 3, t0 = (gid & 7) * BT;
  int tid = threadIdx.x, l = tid & 63, w = tid >> 6;
  int g = w >> 1, half = w & 1;

  // ---- stage x gate half, rows t0-2 .. t0+33, bf16, float4 loads ----
  const float* xb = x + (size_t)b * TT * DIMV + CC;
#pragma unroll 3
  for (int it = 0; it < 9; ++it) {
    int e = tid + it * 256;
    int r = e >> 6, cq = e & 63;
    int t = t0 - 2 + r;
    float4 v = make_float4(0.f, 0.f, 0.f, 0.f);
    if (t >= 0 && t < TT) v = *(const float4*)&xb[(size_t)t * DIMV + 4 * cq];
    *(uint2*)&xs[r * XSTD + 2 * cq] = make_uint2(pack2(v.x, v.y), pack2(v.z, v.w));
  }
  __syncthreads();

  // ---- conv1: M=128 o, N=48 cols (c=0..47; t_out = t0-1+c, valid c<34), K=384 ----
  const short8v* w1p = (const short8v*)w1f;
  int gdw = g * 64;
  f32x4 acc1[2][3];
#pragma unroll
  for (int a = 0; a < 2; ++a)
#pragma unroll
    for (int nt = 0; nt < 3; ++nt) acc1[a][nt] = (f32x4){0.f, 0.f, 0.f, 0.f};

  for (int ks = 0; ks < 12; ++ks) {
    short8v af[2];
#pragma unroll
    for (int a = 0; a < 2; ++a)
      af[a] = w1p[((g * 12 + ks) * 4 + half * 2 + a) * 64 + l];
    int dk = ks >> 2, i0dw = (ks & 3) * 16;
    FragU bf[3];
#pragma unroll
    for (int nt = 0; nt < 3; ++nt) {
      int row = (l & 15) + 16 * nt + dk;
      if (nt == 2) row = row > (XROWS - 1) ? (XROWS - 1) : row;
      const uint4* pp = (const uint4*)&xs[row * XSTD + gdw + i0dw + 4 * (l >> 4)];
      uint4 qv = *pp;
      bf[nt].u[0] = qv.x; bf[nt].u[1] = qv.y; bf[nt].u[2] = qv.z; bf[nt].u[3] = qv.w;
    }
#pragma unroll
    for (int a = 0; a < 2; ++a)
#pragma unroll
      for (int nt = 0; nt < 3; ++nt)
        acc1[a][nt] = __builtin_amdgcn_mfma_f32_16x16x32_bf16(af[a], bf[nt].s, acc1[a][nt], 0, 0, 0);
  }

  // ---- LN1 stats per col ----
#pragma unroll
  for (int nt = 0; nt < 3; ++nt) {
    float s = 0.f, s2 = 0.f;
#pragma unroll
    for (int a = 0; a < 2; ++a)
#pragma unroll
      for (int r = 0; r < 4; ++r) { float v = acc1[a][nt][r]; s += v; s2 += v * v; }
    s += __shfl_xor(s, 16); s += __shfl_xor(s, 32);
    s2 += __shfl_xor(s2, 16); s2 += __shfl_xor(s2, 32);
    if (l < 16) { red1s[w * 48 + l + 16 * nt] = s; red1q[w * 48 + l + 16 * nt] = s2; }
  }
  __syncthreads();

  // ---- apply LN1 + gelu, write h (bf16) to hs ----
#pragma unroll
  for (int nt = 0; nt < 3; ++nt) {
    int c = (l & 15) + 16 * nt;
    if (c < HROWS) {
      int t_out = t0 - 1 + c;
      bool valid = (t_out >= 0 && t_out < TT);
      float S = red1s[0 * 48 + c] + red1s[1 * 48 + c] + red1s[2 * 48 + c] + red1s[3 * 48 + c];
      float S2 = red1q[0 * 48 + c] + red1q[1 * 48 + c] + red1q[2 * 48 + c] + red1q[3 * 48 + c];
      float mean = S * (1.f / 128.f);
      float var = S2 * (1.f / 128.f) - mean * mean;
      float rstd = rsqrtf(var + 1e-5f);
#pragma unroll
      for (int a = 0; a < 2; ++a) {
        int o0 = g * 64 + half * 32 + a * 16 + 4 * (l >> 4);
        float4 gg = *(const float4*)&g1[o0];
        float4 bb = *(const float4*)&b1[o0];
        float gv[4] = {gg.x, gg.y, gg.z, gg.w};
        float bv[4] = {bb.x, bb.y, bb.z, bb.w};
        float h4[4];
#pragma unroll
        for (int r = 0; r < 4; ++r) {
          float xn = (acc1[a][nt][r] - mean) * rstd * gv[r] + bv[r];
          h4[r] = valid ? gelu_f(xn) : 0.f;
        }
        *(uint2*)&hs[c * HSTD + (o0 >> 1)] =
            make_uint2(pack2(h4[0], h4[1]), pack2(h4[2], h4[3]));
      }
    }
  }
  __syncthreads();

  // ---- conv2: M=256 o, N=32 t, K=192 ----
  const short8v* w2p = (const short8v*)w2f;
  int gdw2 = g * 32;
  f32x4 acc2[4][2];
#pragma unroll
  for (int a = 0; a < 4; ++a)
#pragma unroll
    for (int nt = 0; nt < 2; ++nt) acc2[a][nt] = (f32x4){0.f, 0.f, 0.f, 0.f};

  for (int ks = 0; ks < 6; ++ks) {
    short8v af[4];
#pragma unroll
    for (int a = 0; a < 4; ++a)
      af[a] = w2p[((g * 6 + ks) * 8 + half * 4 + a) * 64 + l];
    int dk = ks >> 1, i0dw = (ks & 1) * 16;
    FragU bf[2];
#pragma unroll
    for (int nt = 0; nt < 2; ++nt) {
      int row = (l & 15) + 16 * nt + dk;
      const uint4* pp = (const uint4*)&hs[row * HSTD + gdw2 + i0dw + 4 * (l >> 4)];
      uint4 qv = *pp;
      bf[nt].u[0] = qv.x; bf[nt].u[1] = qv.y; bf[nt].u[2] = qv.z; bf[nt].u[3] = qv.w;
    }
#pragma unroll
    for (int a = 0; a < 4; ++a)
#pragma unroll
      for (int nt = 0; nt < 2; ++nt)
        acc2[a][nt] = __builtin_amdgcn_mfma_f32_16x16x32_bf16(af[a], bf[nt].s, acc2[a][nt], 0, 0, 0);
  }

  // ---- LN2 stats ----
#pragma unroll
  for (int nt = 0; nt < 2; ++nt) {
    float s = 0.f, s2 = 0.f;
#pragma unroll
    for (int a = 0; a < 4; ++a)
#pragma unroll
      for (int r = 0; r < 4; ++r) { float v = acc2[a][nt][r]; s += v; s2 += v * v; }
    s += __shfl_xor(s, 16); s += __shfl_xor(s, 32);
    s2 += __shfl_xor(s2, 16); s2 += __shfl_xor(s2, 32);
    if (l < 16) { red2s[w * 32 + l + 16 * nt] = s; red2q[w * 32 + l + 16 * nt] = s2; }
  }
  __syncthreads();

  // ---- apply LN2 + sigmoid + gate-mul; gate x read from xs (LDS), float4 stores ----
  float* ob = out + (size_t)b * TT * DIMV + CC;
#pragma unroll
  for (int nt = 0; nt < 2; ++nt) {
    int c = (l & 15) + 16 * nt;
    int t = t0 + c;
    if (t < TT) {
      float S = red2s[0 * 32 + c] + red2s[1 * 32 + c] + red2s[2 * 32 + c] + red2s[3 * 32 + c];
      float S2 = red2q[0 * 32 + c] + red2q[1 * 32 + c] + red2q[2 * 32 + c] + red2q[3 * 32 + c];
      float mean = S * (1.f / 256.f);
      float var = S2 * (1.f / 256.f) - mean * mean;
      float rstd = rsqrtf(var + 1e-5f);
      int xrow = c + 2;
#pragma unroll
      for (int a = 0; a < 4; ++a) {
        int o0 = g * 128 + (half * 4 + a) * 16 + 4 * (l >> 4);
        float4 gg = *(const float4*)&g2[o0];
        float4 bb = *(const float4*)&b2[o0];
        float gv[4] = {gg.x, gg.y, gg.z, gg.w};
        float bv[4] = {bb.x, bb.y, bb.z, bb.w};
        uint2 xv2 = *(const uint2*)&xs[xrow * XSTD + (o0 >> 1)];
        float xvv[4] = { b2f((ushort_t)(xv2.x & 0xffff)), b2f((ushort_t)(xv2.x >> 16)),
                         b2f((ushort_t)(xv2.y & 0xffff)), b2f((ushort_t)(xv2.y >> 16)) };
        f32x4 res;
#pragma unroll
        for (int r = 0; r < 4; ++r) {
          float xn = (acc2[a][nt][r] - mean) * rstd * gv[r] + bv[r];
          res[r] = xvv[r] * sigmoid_f(xn);
        }
        *(f32x4*)&ob[(size_t)t * DIMV + o0] = res;
      }
    }
  }
}

__global__ __launch_bounds__(256, 4) void k_main(const float* __restrict__ x,
    const ushort_t* __restrict__ Ffrag,
    const ushort_t* __restrict__ w1f, const float* __restrict__ g1, const float* __restrict__ b1,
    const ushort_t* __restrict__ w2f, const float* __restrict__ g2, const float* __restrict__ b2,
    float* __restrict__ out) {
  __shared__ uint_t smem[SMEM_DW];
  int bid = blockIdx.x;
  int k = bid / 3, r = bid - 3 * k;
  if (r == 0) {
    res_path(k, smem, x, Ffrag, out);
  } else {
    gate_path(2 * k + (r - 1), smem, x, w1f, g1, b1, w2f, g2, b2, out);
  }
}

// ---------------- launch ----------------

extern "C" void kernel_launch(void* const* d_in, const int* in_sizes, int n_in,
                              void* d_out, int out_size, void* d_ws, size_t ws_size,
                              hipStream_t stream) {
  const float* x  = (const float*)d_in[0];
  const float* lf = (const float*)d_in[1];
  const float* w1 = (const float*)d_in[2];
  const float* w2 = (const float*)d_in[3];
  const float* g1 = (const float*)d_in[4];
  const float* b1 = (const float*)d_in[5];
  const float* g2 = (const float*)d_in[6];
  const float* b2 = (const float*)d_in[7];
  float* out = (float*)d_out;

  char* ws = (char*)d_ws;
  float*    A     = (float*)(ws);                   // 237 KB
  ushort_t* Ffrag = (ushort_t*)(ws + 262144);       // 128 KB
  ushort_t* w1f   = (ushort_t*)(ws + 393216);       // 96 KB
  ushort_t* w2f   = (ushort_t*)(ws + 491520);       // 96 KB

  k_prep1<<<FF + 384, 256, 0, stream>>>(lf, A, w1, w2, w1f, w2f);
  k_compute_M<<<256, 256, 0, stream>>>(A, Ffrag);
  k_main<<<BB * 4 * 3, 256, 0, stream>>>(x, Ffrag, w1f, g1, b1, w2f, g2, b2, out);
}

// Round 13
// 211.412 us; speedup vs baseline: 1.0995x; 1.0995x over previous
//
#include <hip/hip_runtime.h>
#include <math.h>

typedef unsigned short ushort_t;
typedef unsigned int uint_t;
typedef __attribute__((ext_vector_type(8))) short short8v;   // 8 bf16 = 4 VGPR
typedef __attribute__((ext_vector_type(4))) float f32x4;

#define BB   512
#define TT   243
#define DIMV 512
#define CC   256
#define CHH  128
#define FF   122
#define NKK  122

__device__ __forceinline__ float b2f(ushort_t u) {
  union { uint_t i; float f; } z; z.i = ((uint_t)u) << 16; return z.f;
}
__device__ __forceinline__ ushort_t f2b(float f) {
  union { float f; uint_t i; } z; z.f = f;
  uint_t r = (z.i + 0x7fffu + ((z.i >> 16) & 1u)) >> 16;
  return (ushort_t)r;
}
// packed f32x2 -> bf16x2 in one VALU instr (RNE)
__device__ __forceinline__ uint_t pack2(float a, float b) {
  uint_t r;
  asm("v_cvt_pk_bf16_f32 %0, %1, %2" : "=v"(r) : "v"(a), "v"(b));
  return r;
}
// branchless gelu: A&S 7.1.26 erf, |eps|<=1.5e-7
__device__ __forceinline__ float gelu_f(float x) {
  float z = fabsf(x) * 0.70710678118654752f;
  float t = __builtin_amdgcn_rcpf(fmaf(0.3275911f, z, 1.0f));
  float p = fmaf(1.061405429f, t, -1.453152027f);
  p = fmaf(p, t, 1.421413741f);
  p = fmaf(p, t, -0.284496736f);
  p = fmaf(p, t, 0.254829592f);
  p = p * t;
  float e = __expf(-z * z);
  float erfa = 1.0f - p * e;
  float erfs = copysignf(erfa, x);
  return 0.5f * x * (1.0f + erfs);
}
__device__ __forceinline__ float sigmoid_f(float x) {
  return __builtin_amdgcn_rcpf(1.0f + __expf(-x));
}
union FragU { uint_t u[4]; short8v s; };

// ---------------- prep1: compute_A (blocks 0..121) + weight pack (blocks 122..505) ----------------

__global__ __launch_bounds__(256) void k_prep1(const float* __restrict__ lf, float* __restrict__ A,
    const float* __restrict__ w1, const float* __restrict__ w2,
    ushort_t* __restrict__ w1f, ushort_t* __restrict__ w2f) {
  __shared__ float2 tab[TT];
  int bid = blockIdx.x;
  if (bid < FF) {
    int f = bid;
    int tp = threadIdx.x;
    if (tp < TT) {
      float s, c;
      sincosf(6.28318530717958647692f * (float)tp / (float)TT, &s, &c);
      tab[tp] = make_float2(s, c);
    }
    __syncthreads();
    if (tp >= TT) return;
    float are = 0.f, aim = 0.f;
    int m = 0;
    const float* lrow = lf + (size_t)f * NKK * 2;
    for (int k = 0; k < NKK; ++k) {
      float2 sc = tab[m];
      float lr = lrow[2 * k], li = lrow[2 * k + 1];
      are = fmaf(lr, sc.y, fmaf(li, sc.x, are));
      aim = fmaf(li, sc.y, fmaf(-lr, sc.x, aim));
      m += tp; if (m >= TT) m -= TT;
    }
    A[(f * TT + tp) * 2 + 0] = are;
    A[(f * TT + tp) * 2 + 1] = aim;
  } else {
    int q = (bid - FF) * 256 + threadIdx.x;
    if (q < 49152) {
      int j = q & 7, l = (q >> 3) & 63, ot = (q >> 9) & 3, rest = q >> 11;
      int ks = rest % 12, g = rest / 12;
      int o = ot * 16 + (l & 15);
      int k = ks * 32 + 8 * (l >> 4) + j;
      int dk = k >> 7, i = k & 127;
      w1f[q] = f2b(w1[(g * 64 + o) * 384 + i * 3 + dk]);
    } else if (q < 98304) {
      int q2 = q - 49152;
      int j = q2 & 7, l = (q2 >> 3) & 63, ot = (q2 >> 9) & 7, rest = q2 >> 12;
      int ks = rest % 6, g = rest / 6;
      int o = ot * 16 + (l & 15);
      int k = ks * 32 + 8 * (l >> 4) + j;
      int dk = k >> 6, i = k & 63;
      w2f[q2] = f2b(w2[(g * 128 + o) * 192 + i * 3 + dk]);
    }
  }
}

// F[t][tp] (256x256 zero-padded) in MFMA fragment order:
// Ffrag[((kstep*16 + mt)*64 + lane)*8 + j] = F[mt*16 + lane%16][kstep*32 + (lane/16)*8 + j]
__global__ void k_compute_M(const float* __restrict__ A, ushort_t* __restrict__ Ffrag) {
  __shared__ float2 tab[TT];
  int t = blockIdx.x;            // 0..255
  int tp = threadIdx.x;          // 0..255
  if (tp < TT) {
    float s, c;
    sincosf(6.28318530717958647692f * (float)tp / (float)TT, &s, &c);
    tab[tp] = make_float2(s, c);
  }
  __syncthreads();
  float val = 0.f;
  if (t < TT && tp < TT) {
    float acc = A[tp * 2 + 0];
    int m = t;
    for (int f = 1; f < FF; ++f) {
      float2 sc = tab[m];
      float ar = A[(f * TT + tp) * 2 + 0];
      float ai = A[(f * TT + tp) * 2 + 1];
      acc = fmaf(2.f * ar, sc.y, fmaf(-2.f * ai, sc.x, acc));
      m += t; if (m >= TT) m -= TT;
    }
    val = acc * (1.0f / (float)TT);
  }
  int kstep = tp >> 5, ko = tp & 31, p = ko >> 3, j = ko & 7;
  int mt = t >> 4, row = t & 15, lane = p * 16 + row;
  Ffrag[(((kstep * 16 + mt) * 64) + lane) * 8 + j] = f2b(val);
}

// ---------------- fused main kernel: res blocks + gate blocks, interleaved 1:2 ----------------

#define RST   17    // res LDS row stride (dwords)
#define BT    32
#define NTIL  8     // ceil(243/32)
#define XROWS 36
#define XSTD  132   // dwords per xs row (256 bf16 + pad); 528B rows: 16B-aligned -> ds_read_b128; 2-way bank = free
#define HROWS 34
#define HSTD  68    // dwords per hs row (128 bf16 + pad); 272B rows: 16B-aligned
// smem dwords: gate = 36*132 + 34*68 + 2*4*48 + 2*4*32 = 7704 ; res = 2*64*17 = 2176
#define SMEM_DW 7704

__device__ __forceinline__ void res_path(int rid, uint_t* smem,
    const float* __restrict__ x, const ushort_t* __restrict__ Ffrag, float* __restrict__ out) {
  uint_t* xs = smem;                            // [2][64*RST]
  int b = rid >> 2, c0 = (rid & 3) * 64;
  int tid = threadIdx.x, l = tid & 63, w = tid >> 6;
  const float* xb = x + (size_t)b * TT * DIMV + c0;
  const short8v* Fp = (const short8v*)Ffrag;

  f32x4 acc[4][4];                              // [q = nt-local][m]
#pragma unroll
  for (int q = 0; q < 4; ++q)
#pragma unroll
    for (int m = 0; m < 4; ++m) acc[q][m] = (f32x4){0.f, 0.f, 0.f, 0.f};

  float v0[4], v1[4];
  int cc = tid & 63, kp0 = tid >> 6;

#pragma unroll
  for (int it = 0; it < 4; ++it) {
    int kp = kp0 + 4 * it, tp = 2 * kp;
    v0[it] = (tp < TT) ? xb[(size_t)tp * DIMV + cc] : 0.f;
    v1[it] = (tp + 1 < TT) ? xb[(size_t)(tp + 1) * DIMV + cc] : 0.f;
  }
#pragma unroll
  for (int it = 0; it < 4; ++it) xs[cc * RST + kp0 + 4 * it] = pack2(v0[it], v1[it]);
  __syncthreads();

  for (int ks = 0; ks < 8; ++ks) {
    int cur = ks & 1;
    if (ks < 7) {
#pragma unroll
      for (int it = 0; it < 4; ++it) {
        int kp = kp0 + 4 * it, tp = (ks + 1) * 32 + 2 * kp;
        v0[it] = (tp < TT) ? xb[(size_t)tp * DIMV + cc] : 0.f;
        v1[it] = (tp + 1 < TT) ? xb[(size_t)(tp + 1) * DIMV + cc] : 0.f;
      }
    }
    FragU bfr[4];
#pragma unroll
    for (int q = 0; q < 4; ++q) bfr[q].s = Fp[(ks * 16 + 4 * w + q) * 64 + l];
#pragma unroll
    for (int m = 0; m < 4; ++m) {
      FragU af;
      const uint_t* pp = &xs[cur * (64 * RST) + (16 * m + (l & 15)) * RST + 4 * (l >> 4)];
      af.u[0] = pp[0]; af.u[1] = pp[1]; af.u[2] = pp[2]; af.u[3] = pp[3];
#pragma unroll
      for (int q = 0; q < 4; ++q)
        acc[q][m] = __builtin_amdgcn_mfma_f32_16x16x32_bf16(af.s, bfr[q].s, acc[q][m], 0, 0, 0);
    }
    if (ks < 7) {
#pragma unroll
      for (int it = 0; it < 4; ++it)
        xs[(cur ^ 1) * (64 * RST) + cc * RST + kp0 + 4 * it] = pack2(v0[it], v1[it]);
    }
    __syncthreads();
  }

  float* ob = out + (size_t)b * TT * DIMV + c0;
#pragma unroll
  for (int q = 0; q < 4; ++q) {
    int t = (4 * w + q) * 16 + (l & 15);
    if (t < TT) {
#pragma unroll
      for (int m = 0; m < 4; ++m)
        *(f32x4*)&ob[(size_t)t * DIMV + 16 * m + 4 * (l >> 4)] = acc[q][m];
    }
  }
}

__device__ __forceinline__ void gate_path(int gid, uint_t* smem,
    const float* __restrict__ x,
    const ushort_t* __restrict__ w1f, const float* __restrict__ g1, const float* __restrict__ b1,
    const ushort_t* __restrict__ w2f, const float* __restrict__ g2, const float* __restrict__ b2,
    float* __restrict__ out) {
  uint_t* xs = smem;                            // [36][132]
  uint_t* hs = smem + XROWS * XSTD;             // [34][68]
  float* red1s = (float*)(hs + HROWS * HSTD);   // [4][48]
  float* red1q = red1s + 192;
  float* red2s = red1q + 192;                   // [4][32]
  float* red2q = red2s + 128;
  int b = gid >> 3, t0 = (gid & 7) * BT;
  int tid = threadIdx.x, l = tid & 63, w = tid >> 6;
  int g = w >> 1, half = w & 1;

  // ---- stage x gate half, rows t0-2 .. t0+33, bf16, float4 loads ----
  const float* xb = x + (size_t)b * TT * DIMV + CC;
#pragma unroll 3
  for (int it = 0; it < 9; ++it) {
    int e = tid + it * 256;
    int r = e >> 6, cq = e & 63;
    int t = t0 - 2 + r;
    float4 v = make_float4(0.f, 0.f, 0.f, 0.f);
    if (t >= 0 && t < TT) v = *(const float4*)&xb[(size_t)t * DIMV + 4 * cq];
    *(uint2*)&xs[r * XSTD + 2 * cq] = make_uint2(pack2(v.x, v.y), pack2(v.z, v.w));
  }
  __syncthreads();

  // ---- conv1: M=128 o, N=48 cols (c=0..47; t_out = t0-1+c, valid c<34), K=384 ----
  const short8v* w1p = (const short8v*)w1f;
  int gdw = g * 64;
  f32x4 acc1[2][3];
#pragma unroll
  for (int a = 0; a < 2; ++a)
#pragma unroll
    for (int nt = 0; nt < 3; ++nt) acc1[a][nt] = (f32x4){0.f, 0.f, 0.f, 0.f};

  for (int ks = 0; ks < 12; ++ks) {
    short8v af[2];
#pragma unroll
    for (int a = 0; a < 2; ++a)
      af[a] = w1p[((g * 12 + ks) * 4 + half * 2 + a) * 64 + l];
    int dk = ks >> 2, i0dw = (ks & 3) * 16;
    FragU bf[3];
#pragma unroll
    for (int nt = 0; nt < 3; ++nt) {
      int row = (l & 15) + 16 * nt + dk;
      if (nt == 2) row = row > (XROWS - 1) ? (XROWS - 1) : row;
      const uint4* pp = (const uint4*)&xs[row * XSTD + gdw + i0dw + 4 * (l >> 4)];
      uint4 qv = *pp;
      bf[nt].u[0] = qv.x; bf[nt].u[1] = qv.y; bf[nt].u[2] = qv.z; bf[nt].u[3] = qv.w;
    }
#pragma unroll
    for (int a = 0; a < 2; ++a)
#pragma unroll
      for (int nt = 0; nt < 3; ++nt)
        acc1[a][nt] = __builtin_amdgcn_mfma_f32_16x16x32_bf16(af[a], bf[nt].s, acc1[a][nt], 0, 0, 0);
  }

  // ---- LN1 stats per col ----
#pragma unroll
  for (int nt = 0; nt < 3; ++nt) {
    float s = 0.f, s2 = 0.f;
#pragma unroll
    for (int a = 0; a < 2; ++a)
#pragma unroll
      for (int r = 0; r < 4; ++r) { float v = acc1[a][nt][r]; s += v; s2 += v * v; }
    s += __shfl_xor(s, 16); s += __shfl_xor(s, 32);
    s2 += __shfl_xor(s2, 16); s2 += __shfl_xor(s2, 32);
    if (l < 16) { red1s[w * 48 + l + 16 * nt] = s; red1q[w * 48 + l + 16 * nt] = s2; }
  }
  __syncthreads();

  // ---- apply LN1 + gelu, write h (bf16) to hs ----
#pragma unroll
  for (int nt = 0; nt < 3; ++nt) {
    int c = (l & 15) + 16 * nt;
    if (c < HROWS) {
      int t_out = t0 - 1 + c;
      bool valid = (t_out >= 0 && t_out < TT);
      float S = red1s[0 * 48 + c] + red1s[1 * 48 + c] + red1s[2 * 48 + c] + red1s[3 * 48 + c];
      float S2 = red1q[0 * 48 + c] + red1q[1 * 48 + c] + red1q[2 * 48 + c] + red1q[3 * 48 + c];
      float mean = S * (1.f / 128.f);
      float var = S2 * (1.f / 128.f) - mean * mean;
      float rstd = rsqrtf(var + 1e-5f);
#pragma unroll
      for (int a = 0; a < 2; ++a) {
        int o0 = g * 64 + half * 32 + a * 16 + 4 * (l >> 4);
        float4 gg = *(const float4*)&g1[o0];
        float4 bb = *(const float4*)&b1[o0];
        float gv[4] = {gg.x, gg.y, gg.z, gg.w};
        float bv[4] = {bb.x, bb.y, bb.z, bb.w};
        float h4[4];
#pragma unroll
        for (int r = 0; r < 4; ++r) {
          float xn = (acc1[a][nt][r] - mean) * rstd * gv[r] + bv[r];
          h4[r] = valid ? gelu_f(xn) : 0.f;
        }
        *(uint2*)&hs[c * HSTD + (o0 >> 1)] =
            make_uint2(pack2(h4[0], h4[1]), pack2(h4[2], h4[3]));
      }
    }
  }
  __syncthreads();

  // ---- conv2: M=256 o, N=32 t, K=192 ----
  const short8v* w2p = (const short8v*)w2f;
  int gdw2 = g * 32;
  f32x4 acc2[4][2];
#pragma unroll
  for (int a = 0; a < 4; ++a)
#pragma unroll
    for (int nt = 0; nt < 2; ++nt) acc2[a][nt] = (f32x4){0.f, 0.f, 0.f, 0.f};

  for (int ks = 0; ks < 6; ++ks) {
    short8v af[4];
#pragma unroll
    for (int a = 0; a < 4; ++a)
      af[a] = w2p[((g * 6 + ks) * 8 + half * 4 + a) * 64 + l];
    int dk = ks >> 1, i0dw = (ks & 1) * 16;
    FragU bf[2];
#pragma unroll
    for (int nt = 0; nt < 2; ++nt) {
      int row = (l & 15) + 16 * nt + dk;
      const uint4* pp = (const uint4*)&hs[row * HSTD + gdw2 + i0dw + 4 * (l >> 4)];
      uint4 qv = *pp;
      bf[nt].u[0] = qv.x; bf[nt].u[1] = qv.y; bf[nt].u[2] = qv.z; bf[nt].u[3] = qv.w;
    }
#pragma unroll
    for (int a = 0; a < 4; ++a)
#pragma unroll
      for (int nt = 0; nt < 2; ++nt)
        acc2[a][nt] = __builtin_amdgcn_mfma_f32_16x16x32_bf16(af[a], bf[nt].s, acc2[a][nt], 0, 0, 0);
  }

  // ---- LN2 stats ----
#pragma unroll
  for (int nt = 0; nt < 2; ++nt) {
    float s = 0.f, s2 = 0.f;
#pragma unroll
    for (int a = 0; a < 4; ++a)
#pragma unroll
      for (int r = 0; r < 4; ++r) { float v = acc2[a][nt][r]; s += v; s2 += v * v; }
    s += __shfl_xor(s, 16); s += __shfl_xor(s, 32);
    s2 += __shfl_xor(s2, 16); s2 += __shfl_xor(s2, 32);
    if (l < 16) { red2s[w * 32 + l + 16 * nt] = s; red2q[w * 32 + l + 16 * nt] = s2; }
  }
  __syncthreads();

  // ---- apply LN2 + sigmoid + gate-mul; gate x read from xs (LDS), float4 stores ----
  float* ob = out + (size_t)b * TT * DIMV + CC;
#pragma unroll
  for (int nt = 0; nt < 2; ++nt) {
    int c = (l & 15) + 16 * nt;
    int t = t0 + c;
    if (t < TT) {
      float S = red2s[0 * 32 + c] + red2s[1 * 32 + c] + red2s[2 * 32 + c] + red2s[3 * 32 + c];
      float S2 = red2q[0 * 32 + c] + red2q[1 * 32 + c] + red2q[2 * 32 + c] + red2q[3 * 32 + c];
      float mean = S * (1.f / 256.f);
      float var = S2 * (1.f / 256.f) - mean * mean;
      float rstd = rsqrtf(var + 1e-5f);
      int xrow = c + 2;
#pragma unroll
      for (int a = 0; a < 4; ++a) {
        int o0 = g * 128 + (half * 4 + a) * 16 + 4 * (l >> 4);
        float4 gg = *(const float4*)&g2[o0];
        float4 bb = *(const float4*)&b2[o0];
        float gv[4] = {gg.x, gg.y, gg.z, gg.w};
        float bv[4] = {bb.x, bb.y, bb.z, bb.w};
        uint2 xv2 = *(const uint2*)&xs[xrow * XSTD + (o0 >> 1)];
        float xvv[4] = { b2f((ushort_t)(xv2.x & 0xffff)), b2f((ushort_t)(xv2.x >> 16)),
                         b2f((ushort_t)(xv2.y & 0xffff)), b2f((ushort_t)(xv2.y >> 16)) };
        f32x4 res;
#pragma unroll
        for (int r = 0; r < 4; ++r) {
          float xn = (acc2[a][nt][r] - mean) * rstd * gv[r] + bv[r];
          res[r] = xvv[r] * sigmoid_f(xn);
        }
        *(f32x4*)&ob[(size_t)t * DIMV + o0] = res;
      }
    }
  }
}

__global__ __launch_bounds__(256, 4) void k_main(const float* __restrict__ x,
    const ushort_t* __restrict__ Ffrag,
    const ushort_t* __restrict__ w1f, const float* __restrict__ g1, const float* __restrict__ b1,
    const ushort_t* __restrict__ w2f, const float* __restrict__ g2, const float* __restrict__ b2,
    float* __restrict__ out) {
  __shared__ uint_t smem[SMEM_DW];
  int bid = blockIdx.x;
  int k = bid / 3, r = bid - 3 * k;
  if (r == 0) {
    res_path(k, smem, x, Ffrag, out);
  } else {
    gate_path(2 * k + (r - 1), smem, x, w1f, g1, b1, w2f, g2, b2, out);
  }
}

// ---------------- launch ----------------

extern "C" void kernel_launch(void* const* d_in, const int* in_sizes, int n_in,
                              void* d_out, int out_size, void* d_ws, size_t ws_size,
                              hipStream_t stream) {
  const float* x  = (const float*)d_in[0];
  const float* lf = (const float*)d_in[1];
  const float* w1 = (const float*)d_in[2];
  const float* w2 = (const float*)d_in[3];
  const float* g1 = (const float*)d_in[4];
  const float* b1 = (const float*)d_in[5];
  const float* g2 = (const float*)d_in[6];
  const float* b2 = (const float*)d_in[7];
  float* out = (float*)d_out;

  char* ws = (char*)d_ws;
  float*    A     = (float*)(ws);                   // 237 KB
  ushort_t* Ffrag = (ushort_t*)(ws + 262144);       // 128 KB
  ushort_t* w1f   = (ushort_t*)(ws + 393216);       // 96 KB
  ushort_t* w2f   = (ushort_t*)(ws + 491520);       // 96 KB

  k_prep1<<<FF + 384, 256, 0, stream>>>(lf, A, w1, w2, w1f, w2f);
  k_compute_M<<<256, 256, 0, stream>>>(A, Ffrag);
  k_main<<<BB * 4 * 3, 256, 0, stream>>>(x, Ffrag, w1f, g1, b1, w2f, g2, b2, out);
}

// Round 14
// 210.934 us; speedup vs baseline: 1.1020x; 1.0023x over previous
//
#include <hip/hip_runtime.h>
#include <math.h>

typedef unsigned short ushort_t;
typedef unsigned int uint_t;
typedef __attribute__((ext_vector_type(8))) short short8v;   // 8 bf16 = 4 VGPR
typedef __attribute__((ext_vector_type(4))) float f32x4;

#define BB   512
#define TT   243
#define DIMV 512
#define CC   256
#define CHH  128
#define FF   122
#define NKK  122

__device__ __forceinline__ float b2f(ushort_t u) {
  union { uint_t i; float f; } z; z.i = ((uint_t)u) << 16; return z.f;
}
__device__ __forceinline__ ushort_t f2b(float f) {
  union { float f; uint_t i; } z; z.f = f;
  uint_t r = (z.i + 0x7fffu + ((z.i >> 16) & 1u)) >> 16;
  return (ushort_t)r;
}
// packed f32x2 -> bf16x2 in one VALU instr (RNE)
__device__ __forceinline__ uint_t pack2(float a, float b) {
  uint_t r;
  asm("v_cvt_pk_bf16_f32 %0, %1, %2" : "=v"(r) : "v"(a), "v"(b));
  return r;
}
// branchless gelu: A&S 7.1.26 erf, |eps|<=1.5e-7
__device__ __forceinline__ float gelu_f(float x) {
  float z = fabsf(x) * 0.70710678118654752f;
  float t = __builtin_amdgcn_rcpf(fmaf(0.3275911f, z, 1.0f));
  float p = fmaf(1.061405429f, t, -1.453152027f);
  p = fmaf(p, t, 1.421413741f);
  p = fmaf(p, t, -0.284496736f);
  p = fmaf(p, t, 0.254829592f);
  p = p * t;
  float e = __expf(-z * z);
  float erfa = 1.0f - p * e;
  float erfs = copysignf(erfa, x);
  return 0.5f * x * (1.0f + erfs);
}
__device__ __forceinline__ float sigmoid_f(float x) {
  return __builtin_amdgcn_rcpf(1.0f + __expf(-x));
}
union FragU { uint_t u[4]; short8v s; };

// ---------------- prep1: compute_A (blocks 0..121) + weight pack (blocks 122..505) ----------------

__global__ __launch_bounds__(256) void k_prep1(const float* __restrict__ lf, float* __restrict__ A,
    const float* __restrict__ w1, const float* __restrict__ w2,
    ushort_t* __restrict__ w1f, ushort_t* __restrict__ w2f) {
  __shared__ float2 tab[TT];
  int bid = blockIdx.x;
  if (bid < FF) {
    int f = bid;
    int tp = threadIdx.x;
    if (tp < TT) {
      float s, c;
      sincosf(6.28318530717958647692f * (float)tp / (float)TT, &s, &c);
      tab[tp] = make_float2(s, c);
    }
    __syncthreads();
    if (tp >= TT) return;
    float are = 0.f, aim = 0.f;
    int m = 0;
    const float* lrow = lf + (size_t)f * NKK * 2;
    for (int k = 0; k < NKK; ++k) {
      float2 sc = tab[m];
      float lr = lrow[2 * k], li = lrow[2 * k + 1];
      are = fmaf(lr, sc.y, fmaf(li, sc.x, are));
      aim = fmaf(li, sc.y, fmaf(-lr, sc.x, aim));
      m += tp; if (m >= TT) m -= TT;
    }
    A[(f * TT + tp) * 2 + 0] = are;
    A[(f * TT + tp) * 2 + 1] = aim;
  } else {
    int q = (bid - FF) * 256 + threadIdx.x;
    if (q < 49152) {
      int j = q & 7, l = (q >> 3) & 63, ot = (q >> 9) & 3, rest = q >> 11;
      int ks = rest % 12, g = rest / 12;
      int o = ot * 16 + (l & 15);
      int k = ks * 32 + 8 * (l >> 4) + j;
      int dk = k >> 7, i = k & 127;
      w1f[q] = f2b(w1[(g * 64 + o) * 384 + i * 3 + dk]);
    } else if (q < 98304) {
      int q2 = q - 49152;
      int j = q2 & 7, l = (q2 >> 3) & 63, ot = (q2 >> 9) & 7, rest = q2 >> 12;
      int ks = rest % 6, g = rest / 6;
      int o = ot * 16 + (l & 15);
      int k = ks * 32 + 8 * (l >> 4) + j;
      int dk = k >> 6, i = k & 63;
      w2f[q2] = f2b(w2[(g * 128 + o) * 192 + i * 3 + dk]);
    }
  }
}

// F[t][tp] (256x256 zero-padded) in MFMA fragment order:
// Ffrag[((kstep*16 + mt)*64 + lane)*8 + j] = F[mt*16 + lane%16][kstep*32 + (lane/16)*8 + j]
__global__ void k_compute_M(const float* __restrict__ A, ushort_t* __restrict__ Ffrag) {
  __shared__ float2 tab[TT];
  int t = blockIdx.x;            // 0..255
  int tp = threadIdx.x;          // 0..255
  if (tp < TT) {
    float s, c;
    sincosf(6.28318530717958647692f * (float)tp / (float)TT, &s, &c);
    tab[tp] = make_float2(s, c);
  }
  __syncthreads();
  float val = 0.f;
  if (t < TT && tp < TT) {
    float acc = A[tp * 2 + 0];
    int m = t;
    for (int f = 1; f < FF; ++f) {
      float2 sc = tab[m];
      float ar = A[(f * TT + tp) * 2 + 0];
      float ai = A[(f * TT + tp) * 2 + 1];
      acc = fmaf(2.f * ar, sc.y, fmaf(-2.f * ai, sc.x, acc));
      m += t; if (m >= TT) m -= TT;
    }
    val = acc * (1.0f / (float)TT);
  }
  int kstep = tp >> 5, ko = tp & 31, p = ko >> 3, j = ko & 7;
  int mt = t >> 4, row = t & 15, lane = p * 16 + row;
  Ffrag[(((kstep * 16 + mt) * 64) + lane) * 8 + j] = f2b(val);
}

// ---------------- fused main kernel: res blocks + gate blocks, interleaved 1:2 ----------------

#define RST   17    // res LDS row stride (dwords)
#define BT    32
#define NTIL  8     // ceil(243/32)
#define XROWS 36
#define XSTD  132   // dwords per xs row (256 bf16 + pad); 528B rows: 16B-aligned -> ds_read_b128; 2-way bank = free
#define HROWS 34
#define HSTD  68    // dwords per hs row (128 bf16 + pad); 272B rows: 16B-aligned
// smem dwords: gate = 36*132 + 34*68 + 2*4*48 + 2*4*32 = 7704 ; res = 2*64*17 = 2176
#define SMEM_DW 7704

__device__ __forceinline__ void res_path(int rid, uint_t* smem,
    const float* __restrict__ x, const ushort_t* __restrict__ Ffrag, float* __restrict__ out) {
  uint_t* xs = smem;                            // [2][64*RST]
  int b = rid >> 2, c0 = (rid & 3) * 64;
  int tid = threadIdx.x, l = tid & 63, w = tid >> 6;
  const float* xb = x + (size_t)b * TT * DIMV + c0;
  const short8v* Fp = (const short8v*)Ffrag;

  f32x4 acc[4][4];                              // [q = nt-local][m]
#pragma unroll
  for (int q = 0; q < 4; ++q)
#pragma unroll
    for (int m = 0; m < 4; ++m) acc[q][m] = (f32x4){0.f, 0.f, 0.f, 0.f};

  float v0[4], v1[4];
  int cc = tid & 63, kp0 = tid >> 6;

#pragma unroll
  for (int it = 0; it < 4; ++it) {
    int kp = kp0 + 4 * it, tp = 2 * kp;
    v0[it] = (tp < TT) ? xb[(size_t)tp * DIMV + cc] : 0.f;
    v1[it] = (tp + 1 < TT) ? xb[(size_t)(tp + 1) * DIMV + cc] : 0.f;
  }
#pragma unroll
  for (int it = 0; it < 4; ++it) xs[cc * RST + kp0 + 4 * it] = pack2(v0[it], v1[it]);
  __syncthreads();

  for (int ks = 0; ks < 8; ++ks) {
    int cur = ks & 1;
    if (ks < 7) {
#pragma unroll
      for (int it = 0; it < 4; ++it) {
        int kp = kp0 + 4 * it, tp = (ks + 1) * 32 + 2 * kp;
        v0[it] = (tp < TT) ? xb[(size_t)tp * DIMV + cc] : 0.f;
        v1[it] = (tp + 1 < TT) ? xb[(size_t)(tp + 1) * DIMV + cc] : 0.f;
      }
    }
    FragU bfr[4];
#pragma unroll
    for (int q = 0; q < 4; ++q) bfr[q].s = Fp[(ks * 16 + 4 * w + q) * 64 + l];
#pragma unroll
    for (int m = 0; m < 4; ++m) {
      FragU af;
      const uint_t* pp = &xs[cur * (64 * RST) + (16 * m + (l & 15)) * RST + 4 * (l >> 4)];
      af.u[0] = pp[0]; af.u[1] = pp[1]; af.u[2] = pp[2]; af.u[3] = pp[3];
#pragma unroll
      for (int q = 0; q < 4; ++q)
        acc[q][m] = __builtin_amdgcn_mfma_f32_16x16x32_bf16(af.s, bfr[q].s, acc[q][m], 0, 0, 0);
    }
    if (ks < 7) {
#pragma unroll
      for (int it = 0; it < 4; ++it)
        xs[(cur ^ 1) * (64 * RST) + cc * RST + kp0 + 4 * it] = pack2(v0[it], v1[it]);
    }
    __syncthreads();
  }

  float* ob = out + (size_t)b * TT * DIMV + c0;
#pragma unroll
  for (int q = 0; q < 4; ++q) {
    int t = (4 * w + q) * 16 + (l & 15);
    if (t < TT) {
#pragma unroll
      for (int m = 0; m < 4; ++m)
        *(f32x4*)&ob[(size_t)t * DIMV + 16 * m + 4 * (l >> 4)] = acc[q][m];
    }
  }
}

__device__ __forceinline__ void gate_path(int gid, uint_t* smem,
    const float* __restrict__ x,
    const ushort_t* __restrict__ w1f, const float* __restrict__ g1, const float* __restrict__ b1,
    const ushort_t* __restrict__ w2f, const float* __restrict__ g2, const float* __restrict__ b2,
    float* __restrict__ out) {
  uint_t* xs = smem;                            // [36][132]
  uint_t* hs = smem + XROWS * XSTD;             // [34][68]
  float* red1s = (float*)(hs + HROWS * HSTD);   // [4][48]
  float* red1q = red1s + 192;
  float* red2s = red1q + 192;                   // [4][32]
  float* red2q = red2s + 128;
  int b = gid >> 3, t0 = (gid & 7) * BT;
  int tid = threadIdx.x, l = tid & 63, w = tid >> 6;
  int g = w >> 1, half = w & 1;

  // ---- stage x gate half, rows t0-2 .. t0+33, bf16, float4 loads ----
  const float* xb = x + (size_t)b * TT * DIMV + CC;
#pragma unroll 3
  for (int it = 0; it < 9; ++it) {
    int e = tid + it * 256;
    int r = e >> 6, cq = e & 63;
    int t = t0 - 2 + r;
    float4 v = make_float4(0.f, 0.f, 0.f, 0.f);
    if (t >= 0 && t < TT) v = *(const float4*)&xb[(size_t)t * DIMV + 4 * cq];
    *(uint2*)&xs[r * XSTD + 2 * cq] = make_uint2(pack2(v.x, v.y), pack2(v.z, v.w));
  }
  __syncthreads();

  // ---- conv1: M=128 o, N=48 cols (c=0..47; t_out = t0-1+c, valid c<34), K=384 ----
  //      weight fragments software-pipelined: load ks+1 before consuming ks
  const short8v* w1p = (const short8v*)w1f;
  int gdw = g * 64;
  f32x4 acc1[2][3];
#pragma unroll
  for (int a = 0; a < 2; ++a)
#pragma unroll
    for (int nt = 0; nt < 3; ++nt) acc1[a][nt] = (f32x4){0.f, 0.f, 0.f, 0.f};

  short8v afc1[2];
#pragma unroll
  for (int a = 0; a < 2; ++a)
    afc1[a] = w1p[((g * 12 + 0) * 4 + half * 2 + a) * 64 + l];

  for (int ks = 0; ks < 12; ++ks) {
    short8v afn1[2];
    if (ks < 11) {
#pragma unroll
      for (int a = 0; a < 2; ++a)
        afn1[a] = w1p[((g * 12 + ks + 1) * 4 + half * 2 + a) * 64 + l];
    }
    int dk = ks >> 2, i0dw = (ks & 3) * 16;
    FragU bf[3];
#pragma unroll
    for (int nt = 0; nt < 3; ++nt) {
      int row = (l & 15) + 16 * nt + dk;
      if (nt == 2) row = row > (XROWS - 1) ? (XROWS - 1) : row;
      const uint4* pp = (const uint4*)&xs[row * XSTD + gdw + i0dw + 4 * (l >> 4)];
      uint4 qv = *pp;
      bf[nt].u[0] = qv.x; bf[nt].u[1] = qv.y; bf[nt].u[2] = qv.z; bf[nt].u[3] = qv.w;
    }
#pragma unroll
    for (int a = 0; a < 2; ++a)
#pragma unroll
      for (int nt = 0; nt < 3; ++nt)
        acc1[a][nt] = __builtin_amdgcn_mfma_f32_16x16x32_bf16(afc1[a], bf[nt].s, acc1[a][nt], 0, 0, 0);
    if (ks < 11) {
#pragma unroll
      for (int a = 0; a < 2; ++a) afc1[a] = afn1[a];
    }
  }

  // ---- LN1 stats per col ----
#pragma unroll
  for (int nt = 0; nt < 3; ++nt) {
    float s = 0.f, s2 = 0.f;
#pragma unroll
    for (int a = 0; a < 2; ++a)
#pragma unroll
      for (int r = 0; r < 4; ++r) { float v = acc1[a][nt][r]; s += v; s2 += v * v; }
    s += __shfl_xor(s, 16); s += __shfl_xor(s, 32);
    s2 += __shfl_xor(s2, 16); s2 += __shfl_xor(s2, 32);
    if (l < 16) { red1s[w * 48 + l + 16 * nt] = s; red1q[w * 48 + l + 16 * nt] = s2; }
  }
  __syncthreads();

  // ---- apply LN1 + gelu, write h (bf16) to hs ----
#pragma unroll
  for (int nt = 0; nt < 3; ++nt) {
    int c = (l & 15) + 16 * nt;
    if (c < HROWS) {
      int t_out = t0 - 1 + c;
      bool valid = (t_out >= 0 && t_out < TT);
      float S = red1s[0 * 48 + c] + red1s[1 * 48 + c] + red1s[2 * 48 + c] + red1s[3 * 48 + c];
      float S2 = red1q[0 * 48 + c] + red1q[1 * 48 + c] + red1q[2 * 48 + c] + red1q[3 * 48 + c];
      float mean = S * (1.f / 128.f);
      float var = S2 * (1.f / 128.f) - mean * mean;
      float rstd = rsqrtf(var + 1e-5f);
#pragma unroll
      for (int a = 0; a < 2; ++a) {
        int o0 = g * 64 + half * 32 + a * 16 + 4 * (l >> 4);
        float4 gg = *(const float4*)&g1[o0];
        float4 bb = *(const float4*)&b1[o0];
        float gv[4] = {gg.x, gg.y, gg.z, gg.w};
        float bv[4] = {bb.x, bb.y, bb.z, bb.w};
        float h4[4];
#pragma unroll
        for (int r = 0; r < 4; ++r) {
          float xn = (acc1[a][nt][r] - mean) * rstd * gv[r] + bv[r];
          h4[r] = valid ? gelu_f(xn) : 0.f;
        }
        *(uint2*)&hs[c * HSTD + (o0 >> 1)] =
            make_uint2(pack2(h4[0], h4[1]), pack2(h4[2], h4[3]));
      }
    }
  }
  __syncthreads();

  // ---- conv2: M=256 o, N=32 t, K=192 (weights software-pipelined) ----
  const short8v* w2p = (const short8v*)w2f;
  int gdw2 = g * 32;
  f32x4 acc2[4][2];
#pragma unroll
  for (int a = 0; a < 4; ++a)
#pragma unroll
    for (int nt = 0; nt < 2; ++nt) acc2[a][nt] = (f32x4){0.f, 0.f, 0.f, 0.f};

  short8v afc2[4];
#pragma unroll
  for (int a = 0; a < 4; ++a)
    afc2[a] = w2p[((g * 6 + 0) * 8 + half * 4 + a) * 64 + l];

  for (int ks = 0; ks < 6; ++ks) {
    short8v afn2[4];
    if (ks < 5) {
#pragma unroll
      for (int a = 0; a < 4; ++a)
        afn2[a] = w2p[((g * 6 + ks + 1) * 8 + half * 4 + a) * 64 + l];
    }
    int dk = ks >> 1, i0dw = (ks & 1) * 16;
    FragU bf[2];
#pragma unroll
    for (int nt = 0; nt < 2; ++nt) {
      int row = (l & 15) + 16 * nt + dk;
      const uint4* pp = (const uint4*)&hs[row * HSTD + gdw2 + i0dw + 4 * (l >> 4)];
      uint4 qv = *pp;
      bf[nt].u[0] = qv.x; bf[nt].u[1] = qv.y; bf[nt].u[2] = qv.z; bf[nt].u[3] = qv.w;
    }
#pragma unroll
    for (int a = 0; a < 4; ++a)
#pragma unroll
      for (int nt = 0; nt < 2; ++nt)
        acc2[a][nt] = __builtin_amdgcn_mfma_f32_16x16x32_bf16(afc2[a], bf[nt].s, acc2[a][nt], 0, 0, 0);
    if (ks < 5) {
#pragma unroll
      for (int a = 0; a < 4; ++a) afc2[a] = afn2[a];
    }
  }

  // ---- LN2 stats ----
#pragma unroll
  for (int nt = 0; nt < 2; ++nt) {
    float s = 0.f, s2 = 0.f;
#pragma unroll
    for (int a = 0; a < 4; ++a)
#pragma unroll
      for (int r = 0; r < 4; ++r) { float v = acc2[a][nt][r]; s += v; s2 += v * v; }
    s += __shfl_xor(s, 16); s += __shfl_xor(s, 32);
    s2 += __shfl_xor(s2, 16); s2 += __shfl_xor(s2, 32);
    if (l < 16) { red2s[w * 32 + l + 16 * nt] = s; red2q[w * 32 + l + 16 * nt] = s2; }
  }
  __syncthreads();

  // ---- apply LN2 + sigmoid + gate-mul; gate x read from xs (LDS), float4 stores ----
  float* ob = out + (size_t)b * TT * DIMV + CC;
#pragma unroll
  for (int nt = 0; nt < 2; ++nt) {
    int c = (l & 15) + 16 * nt;
    int t = t0 + c;
    if (t < TT) {
      float S = red2s[0 * 32 + c] + red2s[1 * 32 + c] + red2s[2 * 32 + c] + red2s[3 * 32 + c];
      float S2 = red2q[0 * 32 + c] + red2q[1 * 32 + c] + red2q[2 * 32 + c] + red2q[3 * 32 + c];
      float mean = S * (1.f / 256.f);
      float var = S2 * (1.f / 256.f) - mean * mean;
      float rstd = rsqrtf(var + 1e-5f);
      int xrow = c + 2;
#pragma unroll
      for (int a = 0; a < 4; ++a) {
        int o0 = g * 128 + (half * 4 + a) * 16 + 4 * (l >> 4);
        float4 gg = *(const float4*)&g2[o0];
        float4 bb = *(const float4*)&b2[o0];
        float gv[4] = {gg.x, gg.y, gg.z, gg.w};
        float bv[4] = {bb.x, bb.y, bb.z, bb.w};
        uint2 xv2 = *(const uint2*)&xs[xrow * XSTD + (o0 >> 1)];
        float xvv[4] = { b2f((ushort_t)(xv2.x & 0xffff)), b2f((ushort_t)(xv2.x >> 16)),
                         b2f((ushort_t)(xv2.y & 0xffff)), b2f((ushort_t)(xv2.y >> 16)) };
        f32x4 res;
#pragma unroll
        for (int r = 0; r < 4; ++r) {
          float xn = (acc2[a][nt][r] - mean) * rstd * gv[r] + bv[r];
          res[r] = xvv[r] * sigmoid_f(xn);
        }
        *(f32x4*)&ob[(size_t)t * DIMV + o0] = res;
      }
    }
  }
}

__global__ __launch_bounds__(256, 4) void k_main(const float* __restrict__ x,
    const ushort_t* __restrict__ Ffrag,
    const ushort_t* __restrict__ w1f, const float* __restrict__ g1, const float* __restrict__ b1,
    const ushort_t* __restrict__ w2f, const float* __restrict__ g2, const float* __restrict__ b2,
    float* __restrict__ out) {
  __shared__ uint_t smem[SMEM_DW];
  int bid = blockIdx.x;
  int k = bid / 3, r = bid - 3 * k;
  if (r == 0) {
    res_path(k, smem, x, Ffrag, out);
  } else {
    gate_path(2 * k + (r - 1), smem, x, w1f, g1, b1, w2f, g2, b2, out);
  }
}

// ---------------- launch ----------------

extern "C" void kernel_launch(void* const* d_in, const int* in_sizes, int n_in,
                              void* d_out, int out_size, void* d_ws, size_t ws_size,
                              hipStream_t stream) {
  const float* x  = (const float*)d_in[0];
  const float* lf = (const float*)d_in[1];
  const float* w1 = (const float*)d_in[2];
  const float* w2 = (const float*)d_in[3];
  const float* g1 = (const float*)d_in[4];
  const float* b1 = (const float*)d_in[5];
  const float* g2 = (const float*)d_in[6];
  const float* b2 = (const float*)d_in[7];
  float* out = (float*)d_out;

  char* ws = (char*)d_ws;
  float*    A     = (float*)(ws);                   // 237 KB
  ushort_t* Ffrag = (ushort_t*)(ws + 262144);       // 128 KB
  ushort_t* w1f   = (ushort_t*)(ws + 393216);       // 96 KB
  ushort_t* w2f   = (ushort_t*)(ws + 491520);       // 96 KB

  k_prep1<<<FF + 384, 256, 0, stream>>>(lf, A, w1, w2, w1f, w2f);
  k_compute_M<<<256, 256, 0, stream>>>(A, Ffrag);
  k_main<<<BB * 4 * 3, 256, 0, stream>>>(x, Ffrag, w1f, g1, b1, w2f, g2, b2, out);
}